// Round 9
// baseline (42.262 us; speedup 1.0000x reference)
//
#include <hip/hip_runtime.h>
#include <stdint.h>

// C51 categorical projection — reg-staged pipeline, 32-row tiles for 2x TLP.
//
// Flat-lever ledger at ~40.5us (3.92 TB/s, 34R/66W mix): occupancy 6/8/12
// blk/CU, depth 2.67/4 iters, gload_lds vs reg-stage, nt stores (FETCH
// byte-identical -> MALL ignores the hint), prefetch distance 1/2. All at
// 2-3 waves/SIMD. This round isolates TLP: 32-row tiles (6.5KB LDS) -> 16
// single-wave blocks/CU = 4 waves/SIMD, GRID 4096 = exactly 4 iters/block.
// Compute confined to lanes 0-31 (VALU ~25% real -> ~50%, still non-binding).
// If flat again: TLP {2,3,4}/SIMD + six structural levers all flat => the
// mixed-stream HBM ceiling is the wall -> declare roofline.
//
// Per iter k (stage regs hold tile k's data on entry):
//   1. ds_write_b128 x7: stage regs -> LDS      (compiler-counted vmcnt wait)
//   2. issue global_load_dwordx4 x7 + r/done    (tile k+G -> regs)
//   3. lanes<32: p[51] <- LDS; zero own slice; stream-emit bins (monotone l_j)
//   4. writeout: 7 x (ds_read_b128 -> nt global_store_dwordx4)
// Single-wave blocks: DS pipe in-order per wave -> no barriers anywhere.

#define ATOMS 51
#define RPB   32                           // rows per block (halved for TLP)
#define THREADS 64
#define TILE_FLOATS (RPB * ATOMS)          // 1632 floats = 6528 B
#define TILE_VECS   (TILE_FLOATS / 4)      // 408
#define VEC_ITERS   ((TILE_VECS + THREADS - 1) / THREADS)  // 7 (last iter: 24 lanes)
#define GRID_MAX 4096                      // 16384 tiles / 4096 = exactly 4 iters/block

typedef float vfloat4 __attribute__((ext_vector_type(4)));

__device__ __forceinline__ void compute_row(float* sb, int t, float rr, float dn) {
    const float c = 0.9f * (1.0f - dn);                      // exactly 0.9 or 0.0
    const float base = fmaf(-16.66666667f, c, (rr + 40.0f) * (1.0f / 2.4f));
    const int ib = t * ATOMS;

    float p[ATOMS];
    #pragma unroll
    for (int j = 0; j < ATOMS; ++j) p[j] = sb[ib + j];

    // zero own 51-float slice (own-row only; other rows owned by other lanes)
    #pragma unroll
    for (int j = 0; j < ATOMS; ++j) sb[ib + j] = 0.0f;

    // scatter-free streaming emit (l_j advances by 0 or 1; c < 1)
    int   cur  = (int)floorf(fminf(fmaxf(base, 0.0f), 50.0f));
    float vcur = 0.0f, vnext = 0.0f;
    #pragma unroll
    for (int j = 0; j < ATOMS; ++j) {
        float b = fmaf(c, (float)j, base);
        b = fminf(fmaxf(b, 0.0f), 50.0f);
        const float lf = floorf(b);
        const float f  = b - lf;
        const int  li  = (int)lf;
        if (li > cur) {
            sb[ib + cur] = vcur;
            vcur = vnext; vnext = 0.0f; ++cur;
        }
        vcur  = fmaf(1.0f - f, p[j], vcur);
        vnext = fmaf(f,        p[j], vnext);
    }
    sb[ib + cur] = vcur;
    if (cur < ATOMS - 1) sb[ib + cur + 1] = vnext;
}

__global__ __launch_bounds__(THREADS) void c51_project(
    const float* __restrict__ prob,
    const float* __restrict__ rin,
    const float* __restrict__ done,
    float* __restrict__ out,
    int nrows)
{
    __shared__ __align__(16) float s_buf[TILE_FLOATS];
    const int t = threadIdx.x;
    const int G = gridDim.x;
    const int ntiles = nrows / RPB;
    const int tail_rows = nrows - ntiles * RPB;

    int tk = blockIdx.x;
    if (tk < ntiles) {
        // ---- prologue: load tile tk + its r/done into regs ----
        vfloat4 stg[VEC_ITERS];
        {
            const vfloat4* gsrc = reinterpret_cast<const vfloat4*>(prob + (size_t)tk * TILE_FLOATS);
            #pragma unroll
            for (int i = 0; i < VEC_ITERS; ++i) {
                const int v = i * THREADS + t;
                stg[i] = (v < TILE_VECS) ? gsrc[v] : (vfloat4){0.f, 0.f, 0.f, 0.f};
            }
        }
        float rv = (t < RPB) ? rin[(size_t)tk * RPB + t]  : 0.f;
        float dv = (t < RPB) ? done[(size_t)tk * RPB + t] : 0.f;

        for (; tk < ntiles; tk += G) {
            // 1. hand staged regs to LDS (compiler inserts the vmcnt wait)
            {
                vfloat4* sv = reinterpret_cast<vfloat4*>(s_buf);
                #pragma unroll
                for (int i = 0; i < VEC_ITERS; ++i) {
                    const int v = i * THREADS + t;
                    if (v < TILE_VECS) sv[v] = stg[i];
                }
            }

            // 2. issue next tile's loads early (latency hides under compute)
            const int nxt = tk + G;
            float rnx = 0.f, dnx = 0.f;
            if (nxt < ntiles) {
                const vfloat4* gsrc = reinterpret_cast<const vfloat4*>(prob + (size_t)nxt * TILE_FLOATS);
                #pragma unroll
                for (int i = 0; i < VEC_ITERS; ++i) {
                    const int v = i * THREADS + t;
                    if (v < TILE_VECS) stg[i] = gsrc[v];
                }
                if (t < RPB) {
                    rnx = rin[(size_t)nxt * RPB + t];
                    dnx = done[(size_t)nxt * RPB + t];
                }
            }
            __builtin_amdgcn_sched_barrier(0);   // keep loads hoisted above compute

            // 3. compute (lanes 0-31 own one row each)
            if (t < RPB) compute_row(s_buf, t, rv, dv);

            // 4. coalesced nt writeout
            {
                vfloat4* dst = reinterpret_cast<vfloat4*>(out + (size_t)tk * TILE_FLOATS);
                const vfloat4* sv = reinterpret_cast<const vfloat4*>(s_buf);
                #pragma unroll
                for (int i = 0; i < VEC_ITERS; ++i) {
                    const int v = i * THREADS + t;
                    if (v < TILE_VECS) __builtin_nontemporal_store(sv[v], &dst[v]);
                }
            }

            rv = rnx; dv = dnx;
        }
    }

    // ---- tail tile (nrows % 32) — block 0, plain path ----
    if (tail_rows > 0 && blockIdx.x == 0) {
        const long long row0 = (long long)ntiles * RPB;
        const int n_e = tail_rows * ATOMS;
        const float* gsrc = prob + (size_t)row0 * ATOMS;
        __syncthreads();
        for (int e = t; e < n_e; e += THREADS) s_buf[e] = gsrc[e];
        __syncthreads();
        if (t < tail_rows) compute_row(s_buf, t, rin[row0 + t], done[row0 + t]);
        __syncthreads();
        float* dst = out + (size_t)row0 * ATOMS;
        for (int e = t; e < n_e; e += THREADS) dst[e] = s_buf[e];
    }
}

extern "C" void kernel_launch(void* const* d_in, const int* in_sizes, int n_in,
                              void* d_out, int out_size, void* d_ws, size_t ws_size,
                              hipStream_t stream) {
    const float* prob = (const float*)d_in[0];
    const float* r    = (const float*)d_in[1];
    const float* done = (const float*)d_in[2];
    float* outp = (float*)d_out;
    const int B = in_sizes[1];               // r: [B,1]
    const int ntiles = B / RPB;
    int grid = ntiles < GRID_MAX ? ntiles : GRID_MAX;
    if (grid < 1) grid = 1;
    c51_project<<<dim3(grid), dim3(THREADS), 0, stream>>>(prob, r, done, outp, B);
}

// Round 10
// 39.753 us; speedup vs baseline: 1.0631x; 1.0631x over previous
//
#include <hip/hip_runtime.h>
#include <stdint.h>

// C51 categorical projection — R7 structure (best known, 40.37us) with one
// change: writeout stores via inline asm `global_store_dwordx4 ... sc0 sc1 nt`
// (full gfx950 cache-policy bypass) instead of plain/nt stores.
//
// Rationale: write stream = 104.5MB/dispatch = 2.59 TB/s = 82% of the copy
// ubench's per-direction rate (3.15 TB/s). Plain stores allocate in per-XCD
// L2 (13MB stream through 4MB -> allocate+evict every line). If that L2
// churn throttles the store pipe, sc0|sc1|nt (no-allocate/write-through)
// recovers it. nt-only (builtin) was proven inert in R7.
//
// Flat-lever ledger (all 40.4-42.3us): occupancy {6,8,12,16} blk/CU,
// waves/SIMD {2,3,4}, depth {2.67,4}, prefetch dist {1,2}, gload_lds vs
// reg-stage, nt stores. If this is flat too -> roofline.
//
// Structure per iter k (stage regs hold tile k's data on entry):
//   1. ds_write_b128 x13: stage regs -> LDS     (compiler-counted vmcnt wait)
//   2. issue global_load_dwordx4 x13 + r/done   (tile k+G -> regs)
//   3. p[51] <- LDS; zero tile (13 b128); stream-emit bins (monotone l_j)
//   4. writeout: 13 x (ds_read_b128 -> asm global_store_dwordx4 sc0 sc1 nt)
// Single-wave blocks: DS pipe in-order per wave -> no barriers anywhere.

#define ATOMS 51
#define RPB   64
#define THREADS 64
#define TILE_FLOATS (RPB * ATOMS)          // 3264 floats = 13056 B
#define TILE_VECS   (TILE_FLOATS / 4)      // 816
#define VEC_ITERS   ((TILE_VECS + THREADS - 1) / THREADS)  // 13 (last iter: 48 lanes)
#define GRID_MAX 2048                      // 8192 tiles / 2048 = exactly 4 iters/block

typedef float vfloat4 __attribute__((ext_vector_type(4)));

__device__ __forceinline__ void compute_row(float* sb, int t, float rr, float dn) {
    const float c = 0.9f * (1.0f - dn);                      // exactly 0.9 or 0.0
    const float base = fmaf(-16.66666667f, c, (rr + 40.0f) * (1.0f / 2.4f));
    const int ib = t * ATOMS;

    float p[ATOMS];
    #pragma unroll
    for (int j = 0; j < ATOMS; ++j) p[j] = sb[ib + j];

    // zero whole tile, flat b128 (DS pipe in-order after the reads above)
    {
        vfloat4* sv = reinterpret_cast<vfloat4*>(sb);
        const vfloat4 z = {0.f, 0.f, 0.f, 0.f};
        #pragma unroll
        for (int i = 0; i < VEC_ITERS; ++i) {
            const int v = i * THREADS + t;
            if (v < TILE_VECS) sv[v] = z;
        }
    }

    // scatter-free streaming emit (l_j advances by 0 or 1; c < 1)
    int   cur  = (int)floorf(fminf(fmaxf(base, 0.0f), 50.0f));
    float vcur = 0.0f, vnext = 0.0f;
    #pragma unroll
    for (int j = 0; j < ATOMS; ++j) {
        float b = fmaf(c, (float)j, base);
        b = fminf(fmaxf(b, 0.0f), 50.0f);
        const float lf = floorf(b);
        const float f  = b - lf;
        const int  li  = (int)lf;
        if (li > cur) {
            sb[ib + cur] = vcur;
            vcur = vnext; vnext = 0.0f; ++cur;
        }
        vcur  = fmaf(1.0f - f, p[j], vcur);
        vnext = fmaf(f,        p[j], vnext);
    }
    sb[ib + cur] = vcur;
    if (cur < ATOMS - 1) sb[ib + cur + 1] = vnext;
}

__global__ __launch_bounds__(THREADS) void c51_project(
    const float* __restrict__ prob,
    const float* __restrict__ rin,
    const float* __restrict__ done,
    float* __restrict__ out,
    int nrows)
{
    __shared__ __align__(16) float s_buf[TILE_FLOATS];
    const int t = threadIdx.x;
    const int G = gridDim.x;
    const int ntiles = nrows / RPB;
    const int tail_rows = nrows - ntiles * RPB;

    int tk = blockIdx.x;
    if (tk < ntiles) {
        // ---- prologue: load tile tk + its r/done into regs ----
        vfloat4 stg[VEC_ITERS];
        {
            const vfloat4* gsrc = reinterpret_cast<const vfloat4*>(prob + (size_t)tk * TILE_FLOATS);
            #pragma unroll
            for (int i = 0; i < VEC_ITERS; ++i) {
                const int v = i * THREADS + t;
                stg[i] = (v < TILE_VECS) ? gsrc[v] : (vfloat4){0.f, 0.f, 0.f, 0.f};
            }
        }
        float rv = rin[(size_t)tk * RPB + t];
        float dv = done[(size_t)tk * RPB + t];

        for (; tk < ntiles; tk += G) {
            // 1. hand staged regs to LDS (compiler inserts the vmcnt wait)
            {
                vfloat4* sv = reinterpret_cast<vfloat4*>(s_buf);
                #pragma unroll
                for (int i = 0; i < VEC_ITERS; ++i) {
                    const int v = i * THREADS + t;
                    if (v < TILE_VECS) sv[v] = stg[i];
                }
            }

            // 2. issue next tile's loads early (latency hides under compute)
            const int nxt = tk + G;
            float rnx = 0.f, dnx = 0.f;
            if (nxt < ntiles) {
                const vfloat4* gsrc = reinterpret_cast<const vfloat4*>(prob + (size_t)nxt * TILE_FLOATS);
                #pragma unroll
                for (int i = 0; i < VEC_ITERS; ++i) {
                    const int v = i * THREADS + t;
                    if (v < TILE_VECS) stg[i] = gsrc[v];
                }
                rnx = rin[(size_t)nxt * RPB + t];
                dnx = done[(size_t)nxt * RPB + t];
            }
            __builtin_amdgcn_sched_barrier(0);   // keep loads hoisted above compute

            // 3-5. compute (reads row, zeroes tile, streams bins back)
            compute_row(s_buf, t, rv, dv);

            // 6. coalesced writeout — L2-bypass stores (sc0 sc1 nt): out has
            //    zero reuse; don't let 13MB/XCD/dispatch churn the 4MB L2.
            {
                const vfloat4* sv = reinterpret_cast<const vfloat4*>(s_buf);
                float* gbase = out + (size_t)tk * TILE_FLOATS;
                #pragma unroll
                for (int i = 0; i < VEC_ITERS; ++i) {
                    const int v = i * THREADS + t;
                    if (v < TILE_VECS) {
                        vfloat4 val = sv[v];
                        const float* addr = gbase + (size_t)v * 4;
                        asm volatile("global_store_dwordx4 %0, %1, off sc0 sc1 nt"
                                     :: "v"(addr), "v"(val) : "memory");
                    }
                }
            }

            rv = rnx; dv = dnx;
        }
    }

    // ---- tail tile (nrows % 64) — block 0, plain path ----
    if (tail_rows > 0 && blockIdx.x == 0) {
        const long long row0 = (long long)ntiles * RPB;
        const int n_e = tail_rows * ATOMS;
        const float* gsrc = prob + (size_t)row0 * ATOMS;
        __syncthreads();
        for (int e = t; e < n_e; e += THREADS) s_buf[e] = gsrc[e];
        __syncthreads();
        if (t < tail_rows) compute_row(s_buf, t, rin[row0 + t], done[row0 + t]);
        __syncthreads();
        float* dst = out + (size_t)row0 * ATOMS;
        for (int e = t; e < n_e; e += THREADS) dst[e] = s_buf[e];
    }
}

extern "C" void kernel_launch(void* const* d_in, const int* in_sizes, int n_in,
                              void* d_out, int out_size, void* d_ws, size_t ws_size,
                              hipStream_t stream) {
    const float* prob = (const float*)d_in[0];
    const float* r    = (const float*)d_in[1];
    const float* done = (const float*)d_in[2];
    float* outp = (float*)d_out;
    const int B = in_sizes[1];               // r: [B,1]
    const int ntiles = B / RPB;
    int grid = ntiles < GRID_MAX ? ntiles : GRID_MAX;
    if (grid < 1) grid = 1;
    c51_project<<<dim3(grid), dim3(THREADS), 0, stream>>>(prob, r, done, outp, B);
}